// Round 8
// baseline (163.929 us; speedup 1.0000x reference)
//
#include <hip/hip_runtime.h>
#include <hip/hip_bf16.h>

#define HWHW 65536   // 256*256
#define LN1E4_32 0.28782313662425572f   // ln(10000)/32
#define TWO_PI_N 6.2831847f              // 2*pi / 1.000001

typedef __attribute__((ext_vector_type(8))) short short8;
typedef __attribute__((ext_vector_type(4))) short s16x4;   // 'short4' taken by HIP
typedef __attribute__((ext_vector_type(4))) float f32x4;

// d_ws layout:
//   [0, 32768)        : wfrag bf16 — Q slots 0..1023 (K=128), K' 1024..1535,
//                       V' 1536..2047 (K=64, pair-summed weights)
//   [32768, 34816)    : bias tables fp32 — peK·Wk+k_b [4][64], then peV·Wv+v_b
//   [65536, 16842752) : feat_supp transposed (B,HW,C) bf16
// REQUIRES ws_size >= 16842752.

__device__ __forceinline__ short f2bf(float f) {
  union { __hip_bfloat16 h; short s; } u;
  u.h = __float2bfloat16(f);
  return u.s;
}

// ---------------- merged pre-pass (R1 version — measured ~BW-floor, keep):
//   blocks 0..2047    : feat_supp (B,C,HW) f32 -> (B,HW,C) bf16 transpose
//   blocks 2048..2055 : weight fragment packing
//   block  2056       : PE-folded bias tables
__global__ __launch_bounds__(256)
void pre_pass(const float* __restrict__ supp,
              const float* __restrict__ qw, const float* __restrict__ kw,
              const float* __restrict__ vw,
              const float* __restrict__ kb, const float* __restrict__ vb,
              __hip_bfloat16* __restrict__ suppT,
              __hip_bfloat16* __restrict__ wfrag, float* __restrict__ bias) {
  const int t = threadIdx.x;
  if (blockIdx.x < 2048) {
    __shared__ short tile[64 * 68];     // 8.7 KB
    const int b   = blockIdx.x >> 10;
    const int p0  = (blockIdx.x & 1023) << 6;
    const int px4 = (t & 15) << 2;      // pixel group 0,4,..,60
    const int g   = t >> 4;             // channel quad 0..15

    const float* src = supp + ((size_t)b * 64 + g * 4) * HWHW + p0 + px4;
    f32x4 v[4];
#pragma unroll
    for (int c = 0; c < 4; ++c)
      v[c] = *(const f32x4*)(src + (size_t)c * HWHW);
#pragma unroll
    for (int j = 0; j < 4; ++j) {
      s16x4 pk;
#pragma unroll
      for (int c = 0; c < 4; ++c) pk[c] = f2bf(v[c][j]);
      *(s16x4*)&tile[(px4 + j) * 68 + g * 4] = pk;
    }
    __syncthreads();
    const int px = t >> 2, ch0 = (t & 3) << 4;
    s16x4 r0 = *(s16x4*)&tile[px * 68 + ch0];
    s16x4 r1 = *(s16x4*)&tile[px * 68 + ch0 + 4];
    s16x4 r2 = *(s16x4*)&tile[px * 68 + ch0 + 8];
    s16x4 r3 = *(s16x4*)&tile[px * 68 + ch0 + 12];
    short8 o0, o1;
#pragma unroll
    for (int j = 0; j < 4; ++j) {
      o0[j] = r0[j]; o0[j + 4] = r1[j];
      o1[j] = r2[j]; o1[j + 4] = r3[j];
    }
    short8* dst = (short8*)(suppT + ((size_t)(b * HWHW + p0 + px)) * 64 + ch0);
    dst[0] = o0;
    dst[1] = o1;
  } else if (blockIdx.x < 2056) {
    // ---- weight fragments. B layout: n=nt*16+(lane&15), k=ks*32+(lane>>4)*8+j
    int slot = (blockIdx.x - 2048) * 256 + t;     // 0..2047
    __hip_bfloat16* dst = wfrag + slot * 8;
    if (slot < 1024) {               // Q (K=128)
      int ksnt = slot >> 6, lane = slot & 63;
      int ks = ksnt >> 2, nt = ksnt & 3;
      const float* w = qw + (nt * 16 + (lane & 15)) * 128 + ks * 32 + (lane >> 4) * 8;
#pragma unroll
      for (int j = 0; j < 8; ++j) dst[j] = __float2bfloat16(w[j]);
    } else {                         // K'/V': K=64, W'[n][c] = W[n][2c]+W[n][2c+1]
      int mat = (slot >= 1536);
      int rem = slot & 511;
      int ksnt = rem >> 6, lane = rem & 63;
      int ks = ksnt >> 2, nt = ksnt & 3;          // ks 0..1
      int c0 = ks * 32 + (lane >> 4) * 8;
      const float* w = (mat ? vw : kw) + (nt * 16 + (lane & 15)) * 128;
#pragma unroll
      for (int j = 0; j < 8; ++j)
        dst[j] = __float2bfloat16(w[2 * (c0 + j)] + w[2 * (c0 + j) + 1]);
    }
  } else {
    // ---- bias[mat*256 + uv*64 + c] = b[c] + sum_kk pe[uv][kk] * W[c][kk]
    for (int s = t; s < 512; s += 256) {
      int mat = s >> 8, uv = (s >> 6) & 3, c = s & 63;
      const float* w = (mat ? vw : kw) + c * 128;
      float acc = (mat ? vb : kb)[c];
      for (int kk = 0; kk < 128; ++kk) {
        float val = (kk < 64 ? (float)(uv >> 1) : (float)(uv & 1)) * TWO_PI_N;
        int i = kk & 63, f = i >> 1;
        float arg = val * __expf(-(float)f * LN1E4_32);
        float pe = (i & 1) ? __cosf(arg) : __sinf(arg);
        acc += pe * w[kk];
      }
      bias[s] = acc;
    }
  }
}

// ---------------- main: 64 px/block, 4 waves.
// R8: R7 regression autopsy — per-use GLOBAL weight reads put L2 latency
// on the critical path (R5 LDS weights: 42.4 us; R7 global: 50 us).
// Weights go back to LDS, but LDS shrinks 34.5K -> 26K for 6 blocks/CU:
//  (a) ONE 16 KB weight buffer time-shared: stage Qw -> Q MFMAs ->
//      barrier -> restage K'/V' into the same bytes (bulk-coalesced,
//      once per block) -> KV loop.
//  (b) outstage halved to 32x64 f32 (8 KB): nt={0,1} -> readout rows
//      0..31 -> nt={2,3} -> readout rows 32..63. Stride-65 padding
//      replaced by rotation swizzle addr = r*64 + ((p+c)&63)
//      (write <=4-way, read conflict-free, bijective per row).
//  LDS total 26624 (+256 runtime overhead = 26880) -> 6 blocks/CU,
//  24 waves vs R5's 16. waves_per_eu(5,8): safe 102-reg budget (R5/R7
//  compiled 64/48); 6 waves/SIMD materializes if VGPR <= 85.
// DPP softmax reduce kept from R7 (bank-conflict counter proved neutral).
// Spill tripwire: WRITE_SIZE must stay 32768 KB.
__global__ __attribute__((amdgpu_waves_per_eu(5, 8))) __launch_bounds__(256)
void iw_main(const __hip_bfloat16* __restrict__ suppT, const float* __restrict__ flow,
             const float* __restrict__ feat_curr,
             const short8* __restrict__ wg, const float* __restrict__ bias_g,
             const float* __restrict__ q_b, float* __restrict__ out)
{
  // LDS map: [0,16384)     weight buffer (Q frags, then K'/V' frags)
  //          [16384,18432) bias as [mat][nt][l15][r] f32 (b128 per lane)
  //          [18432,26624) outstage 32x64 f32, rotation-swizzled
  __shared__ __align__(16) char smem[26624];
  short8* lds_w    = (short8*)smem;
  f32x4*  lds_bias = (f32x4*)(smem + 16384);
  float*  outst    = (float*)(smem + 18432);

  const int tid = threadIdx.x;
  const int idx = ((blockIdx.x & 7) << 8) | (blockIdx.x >> 3);  // XCD swizzle
  const int b   = idx >> 10;
  const int hw0 = (idx & 1023) << 6;
  const int lane = tid & 63, wv = tid >> 6;
  const int quad = lane >> 4, l15 = lane & 15;
  const int uvl  = l15 & 3;
  const int prow = l15 >> 2;
  const short8* sT = (const short8*)suppT;   // 8 short8 per pixel

  // ---------- stage Q weights (slots 0..1023) + bias into LDS
#pragma unroll
  for (int j = 0; j < 4; ++j)
    lds_w[j * 256 + tid] = wg[j * 256 + tid];
  {
    float* bl = (float*)lds_bias;
#pragma unroll
    for (int s_ = 0; s_ < 2; ++s_) {
      int s = s_ * 256 + tid;
      int mat = s >> 8, rem = s & 255, r = rem >> 6, c = rem & 63;
      bl[mat * 256 + (c >> 4) * 64 + (c & 15) * 4 + r] = bias_g[s];
    }
  }
  __syncthreads();                                   // B1: Qw staged

  // per-lane inverse dim_t: f = a*16 + quad*4 + jj
  float invd[2][4];
#pragma unroll
  for (int a = 0; a < 2; ++a)
#pragma unroll
    for (int jj = 0; jj < 4; ++jj)
      invd[a][jj] = __expf(-(float)(a * 16 + quad * 4 + jj) * LN1E4_32);

  int iy, ix;              // integer grid base of this lane's Q pixel
  f32x4 qacc[4];

  // ---------- Q phase: A-frag (m = l15 -> pixel), GEMM (K=128), B from LDS
  {
    const int qpix = hw0 + wv * 16 + l15;
    float2 fl = ((const float2*)flow)[b * HWHW + qpix];
    float gy = (float)(qpix >> 8) + fl.y;
    float gx = (float)(qpix & 255) + fl.x;
    float fy = floorf(gy), fx = floorf(gx);
    iy = (int)fy; ix = (int)fx;
    float vy = (gy - fy) * (6.2831853071795864f / 2.000001f);
    float vx = (gx - fx) * (6.2831853071795864f / 2.000001f);

    short8 qa[4];
#pragma unroll
    for (int ks = 0; ks < 4; ++ks) {
      float val = (ks < 2) ? vy : vx;
#pragma unroll
      for (int jj = 0; jj < 4; ++jj) {
        int c = ks * 16 + quad * 4 + jj;
        float feat = feat_curr[(b * 64 + c) * HWHW + qpix];
        float arg = val * invd[ks & 1][jj];
        qa[ks][jj * 2]     = f2bf(feat + __sinf(arg));
        qa[ks][jj * 2 + 1] = f2bf(feat + __cosf(arg));
      }
    }
#pragma unroll
    for (int nt = 0; nt < 4; ++nt) qacc[nt] = (f32x4){0.f, 0.f, 0.f, 0.f};
#pragma unroll
    for (int ks = 0; ks < 4; ++ks)
#pragma unroll
      for (int nt = 0; nt < 4; ++nt)
        qacc[nt] = __builtin_amdgcn_mfma_f32_16x16x32_bf16(
            qa[ks], lds_w[(ks * 4 + nt) * 64 + lane], qacc[nt], 0, 0, 0);
  }

  // ---------- gather offsets for all mt, from in-register iy/ix
  int off[4];
#pragma unroll
  for (int m = 0; m < 4; ++m) {
    int p  = m * 4 + prow;
    int yy = min(max(__shfl(iy, p) + (uvl >> 1), 0), 255);
    int xx = min(max(__shfl(ix, p) + (uvl & 1), 0), 255);
    off[m] = (b * HWHW + yy * 256 + xx) * 8;
  }

  __syncthreads();                                   // B2: Qw reads done

  // ---------- restage K'/V' into the SAME weight bytes; issue all 8
  // gathers alongside (12 loads in flight, covered by the qT transpose)
  short8 s0 = wg[1024 + tid];
  short8 s1 = wg[1280 + tid];
  short8 s2 = wg[1536 + tid];
  short8 s3 = wg[1792 + tid];
  short8 ka[4][2];
#pragma unroll
  for (int m = 0; m < 4; ++m) {
    ka[m][0] = sT[off[m] + quad];
    ka[m][1] = sT[off[m] + 4 + quad];
  }

  // bias+scale then shuffle-transpose: qT[mt][nt] = q[pixel mt*4+quad][nt*16+l15]
  float qT[4][4];
  {
#pragma unroll
    for (int nt = 0; nt < 4; ++nt) {
      float qb = q_b[nt * 16 + l15];
#pragma unroll
      for (int r = 0; r < 4; ++r)
        qacc[nt][r] = (qacc[nt][r] + qb) * 0.35355339059327373f;
    }
#pragma unroll
    for (int mt = 0; mt < 4; ++mt)
#pragma unroll
      for (int nt = 0; nt < 4; ++nt) {
        int src = mt * 16 + l15;
        float v0 = __shfl(qacc[nt][0], src);
        float v1 = __shfl(qacc[nt][1], src);
        float v2 = __shfl(qacc[nt][2], src);
        float v3 = __shfl(qacc[nt][3], src);
        float t0 = (quad & 2) ? v2 : v0;
        float t1 = (quad & 2) ? v3 : v1;
        qT[mt][nt] = (quad & 1) ? t1 : t0;
      }
  }

  lds_w[tid]       = s0;
  lds_w[256 + tid] = s1;
  lds_w[512 + tid] = s2;
  lds_w[768 + tid] = s3;
  __syncthreads();                                   // B3: KV staged

  // ---------- K/V + attention in two halves (outstage holds 32 rows)
#pragma unroll
  for (int half = 0; half < 2; ++half) {
#pragma unroll
    for (int nth = 0; nth < 2; ++nth) {
      const int nt = half * 2 + nth;
      short8 kf0 = lds_w[nt * 64 + lane];
      short8 kf1 = lds_w[(4 + nt) * 64 + lane];
      short8 vf0 = lds_w[(8 + nt) * 64 + lane];
      short8 vf1 = lds_w[(12 + nt) * 64 + lane];
      f32x4 kb4 = lds_bias[nt * 16 + l15];        // [0][nt][l15][r]
      f32x4 vb4 = lds_bias[64 + nt * 16 + l15];   // [1][nt][l15][r]

#pragma unroll
      for (int mt = 0; mt < 4; ++mt) {
        f32x4 kacc = kb4;   // bias rides in the MFMA C-operand (reg r == uv r)
        f32x4 vacc = vb4;
        kacc = __builtin_amdgcn_mfma_f32_16x16x32_bf16(ka[mt][0], kf0, kacc, 0, 0, 0);
        kacc = __builtin_amdgcn_mfma_f32_16x16x32_bf16(ka[mt][1], kf1, kacc, 0, 0, 0);
        vacc = __builtin_amdgcn_mfma_f32_16x16x32_bf16(ka[mt][0], vf0, vacc, 0, 0, 0);
        vacc = __builtin_amdgcn_mfma_f32_16x16x32_bf16(ka[mt][1], vf1, vacc, 0, 0, 0);

        // D rows: pixel = mt*4+quad, uv = reg r. Head channels span 8 lanes.
        // 8-lane sum via DPP: xor1 (0xB1), xor2 (0x4E), row_half_mirror
        // (0x141) — valid: quad sums are uniform per quad at the last step.
        float lg[4];
#pragma unroll
        for (int r = 0; r < 4; ++r) {
          float p = qT[mt][nt] * kacc[r];
          p += __int_as_float(__builtin_amdgcn_update_dpp(
                   0, __float_as_int(p), 0xB1, 0xf, 0xf, true));
          p += __int_as_float(__builtin_amdgcn_update_dpp(
                   0, __float_as_int(p), 0x4E, 0xf, 0xf, true));
          p += __int_as_float(__builtin_amdgcn_update_dpp(
                   0, __float_as_int(p), 0x141, 0xf, 0xf, true));
          lg[r] = p;
        }
        float mx = fmaxf(fmaxf(lg[0], lg[1]), fmaxf(lg[2], lg[3]));
        float e0 = __expf(lg[0] - mx), e1 = __expf(lg[1] - mx);
        float e2 = __expf(lg[2] - mx), e3 = __expf(lg[3] - mx);
        float inv = 1.0f / (e0 + e1 + e2 + e3);
        float o = (e0 * vacc[0] + e1 * vacc[1] + e2 * vacc[2] + e3 * vacc[3]) * inv;
        // rotation-swizzled outstage: row r = c&31, col (p + c) & 63
        int c = nt * 16 + l15;
        int p_ = wv * 16 + mt * 4 + quad;
        outst[((nt & 1) * 16 + l15) * 64 + ((p_ + c) & 63)] = o;
      }
    }
    __syncthreads();                                 // half's rows complete
#pragma unroll
    for (int i = 0; i < 8; ++i) {
      int r = i * 4 + wv;
      int c = half * 32 + r;
      out[(b * 64 + c) * HWHW + hw0 + lane] = outst[r * 64 + ((lane + c) & 63)];
    }
    if (half == 0) __syncthreads();                  // readout done, rows reusable
  }
}

extern "C" void kernel_launch(void* const* d_in, const int* in_sizes, int n_in,
                              void* d_out, int out_size, void* d_ws, size_t ws_size,
                              hipStream_t stream) {
  const float* feat_supp = (const float*)d_in[0];
  const float* flow      = (const float*)d_in[1];
  const float* feat_curr = (const float*)d_in[2];
  const float* q_w = (const float*)d_in[3];
  const float* q_b = (const float*)d_in[4];
  const float* k_w = (const float*)d_in[5];
  const float* k_b = (const float*)d_in[6];
  const float* v_w = (const float*)d_in[7];
  const float* v_b = (const float*)d_in[8];
  float* out = (float*)d_out;
  (void)in_sizes; (void)n_in; (void)out_size; (void)ws_size;

  __hip_bfloat16* wfrag = (__hip_bfloat16*)d_ws;
  float* bias           = (float*)((char*)d_ws + 32768);
  __hip_bfloat16* suppT = (__hip_bfloat16*)((char*)d_ws + 65536);

  hipLaunchKernelGGL(pre_pass, dim3(2057), dim3(256), 0, stream,
                     feat_supp, q_w, k_w, v_w, k_b, v_b, suppT, wfrag, bias);
  hipLaunchKernelGGL(iw_main, dim3(2048), dim3(256), 0, stream,
                     suppT, flow, feat_curr, (const short8*)d_ws, bias, q_b, out);
}

// Round 9
// 146.325 us; speedup vs baseline: 1.1203x; 1.1203x over previous
//
#include <hip/hip_runtime.h>
#include <hip/hip_bf16.h>

#define HWHW 65536   // 256*256
#define LN1E4_32 0.28782313662425572f   // ln(10000)/32
#define TWO_PI_N 6.2831847f              // 2*pi / 1.000001

typedef __attribute__((ext_vector_type(8))) short short8;
typedef __attribute__((ext_vector_type(4))) short s16x4;   // 'short4' taken by HIP
typedef __attribute__((ext_vector_type(4))) float f32x4;

// native-revolution trig: v_sin_f32/v_cos_f32 take REVOLUTIONS (ISA).
// rev inputs here are in [0, 0.5] so no range reduction is needed.
#if __has_builtin(__builtin_amdgcn_sinf) && __has_builtin(__builtin_amdgcn_cosf)
#define FSIN(x) __builtin_amdgcn_sinf(x)
#define FCOS(x) __builtin_amdgcn_cosf(x)
#else
#define FSIN(x) __sinf((x) * 6.2831853071795864f)
#define FCOS(x) __cosf((x) * 6.2831853071795864f)
#endif

// d_ws layout:
//   [0, 32768)        : wfrag bf16 — Q slots 0..1023 (K=128), K' 1024..1535,
//                       V' 1536..2047 (K=64, pair-summed weights)
//   [32768, 34816)    : bias tables fp32 — peK·Wk+k_b [4][64], then peV·Wv+v_b
//   [65536, 16842752) : feat_supp transposed (B,HW,C) bf16
// REQUIRES ws_size >= 16842752.

__device__ __forceinline__ short f2bf(float f) {
  union { __hip_bfloat16 h; short s; } u;
  u.h = __float2bfloat16(f);
  return u.s;
}

// ---------------- merged pre-pass (R1 version — measured ~BW-floor, keep):
//   blocks 0..2047    : feat_supp (B,C,HW) f32 -> (B,HW,C) bf16 transpose
//   blocks 2048..2055 : weight fragment packing
//   block  2056       : PE-folded bias tables
__global__ __launch_bounds__(256)
void pre_pass(const float* __restrict__ supp,
              const float* __restrict__ qw, const float* __restrict__ kw,
              const float* __restrict__ vw,
              const float* __restrict__ kb, const float* __restrict__ vb,
              __hip_bfloat16* __restrict__ suppT,
              __hip_bfloat16* __restrict__ wfrag, float* __restrict__ bias) {
  const int t = threadIdx.x;
  if (blockIdx.x < 2048) {
    __shared__ short tile[64 * 68];     // 8.7 KB
    const int b   = blockIdx.x >> 10;
    const int p0  = (blockIdx.x & 1023) << 6;
    const int px4 = (t & 15) << 2;      // pixel group 0,4,..,60
    const int g   = t >> 4;             // channel quad 0..15

    const float* src = supp + ((size_t)b * 64 + g * 4) * HWHW + p0 + px4;
    f32x4 v[4];
#pragma unroll
    for (int c = 0; c < 4; ++c)
      v[c] = *(const f32x4*)(src + (size_t)c * HWHW);
#pragma unroll
    for (int j = 0; j < 4; ++j) {
      s16x4 pk;
#pragma unroll
      for (int c = 0; c < 4; ++c) pk[c] = f2bf(v[c][j]);
      *(s16x4*)&tile[(px4 + j) * 68 + g * 4] = pk;
    }
    __syncthreads();
    const int px = t >> 2, ch0 = (t & 3) << 4;
    s16x4 r0 = *(s16x4*)&tile[px * 68 + ch0];
    s16x4 r1 = *(s16x4*)&tile[px * 68 + ch0 + 4];
    s16x4 r2 = *(s16x4*)&tile[px * 68 + ch0 + 8];
    s16x4 r3 = *(s16x4*)&tile[px * 68 + ch0 + 12];
    short8 o0, o1;
#pragma unroll
    for (int j = 0; j < 4; ++j) {
      o0[j] = r0[j]; o0[j + 4] = r1[j];
      o1[j] = r2[j]; o1[j + 4] = r3[j];
    }
    short8* dst = (short8*)(suppT + ((size_t)(b * HWHW + p0 + px)) * 64 + ch0);
    dst[0] = o0;
    dst[1] = o1;
  } else if (blockIdx.x < 2056) {
    // ---- weight fragments. B layout: n=nt*16+(lane&15), k=ks*32+(lane>>4)*8+j
    int slot = (blockIdx.x - 2048) * 256 + t;     // 0..2047
    __hip_bfloat16* dst = wfrag + slot * 8;
    if (slot < 1024) {               // Q (K=128)
      int ksnt = slot >> 6, lane = slot & 63;
      int ks = ksnt >> 2, nt = ksnt & 3;
      const float* w = qw + (nt * 16 + (lane & 15)) * 128 + ks * 32 + (lane >> 4) * 8;
#pragma unroll
      for (int j = 0; j < 8; ++j) dst[j] = __float2bfloat16(w[j]);
    } else {                         // K'/V': K=64, W'[n][c] = W[n][2c]+W[n][2c+1]
      int mat = (slot >= 1536);
      int rem = slot & 511;
      int ksnt = rem >> 6, lane = rem & 63;
      int ks = ksnt >> 2, nt = ksnt & 3;          // ks 0..1
      int c0 = ks * 32 + (lane >> 4) * 8;
      const float* w = (mat ? vw : kw) + (nt * 16 + (lane & 15)) * 128;
#pragma unroll
      for (int j = 0; j < 8; ++j)
        dst[j] = __float2bfloat16(w[2 * (c0 + j)] + w[2 * (c0 + j) + 1]);
    }
  } else {
    // ---- bias[mat*256 + uv*64 + c] = b[c] + sum_kk pe[uv][kk] * W[c][kk]
    for (int s = t; s < 512; s += 256) {
      int mat = s >> 8, uv = (s >> 6) & 3, c = s & 63;
      const float* w = (mat ? vw : kw) + c * 128;
      float acc = (mat ? vb : kb)[c];
      for (int kk = 0; kk < 128; ++kk) {
        float val = (kk < 64 ? (float)(uv >> 1) : (float)(uv & 1)) * TWO_PI_N;
        int i = kk & 63, f = i >> 1;
        float arg = val * __expf(-(float)f * LN1E4_32);
        float pe = (i & 1) ? __cosf(arg) : __sinf(arg);
        acc += pe * w[kk];
      }
      bias[s] = acc;
    }
  }
}

// ---------------- main: 64 px/block, 4 waves.
// R9 = R5 structure EXACTLY (best measured: 42.4 us) + VALU trims.
// Structure evidence: R7 (18.9K LDS, 8 blocks possible) and R8 (26.6K,
// 6 blocks) both REGRESSED vs R5 (34.5K, 4 blocks) — measured occupancy
// never exceeded ~38% regardless of resources (grid is only 8 blocks/CU
// total; residency beyond divisors of 8 creates drain tail), and both
// paid critical-path costs (R7: per-use L2 weight latency; R8: +2
// barriers + serialized KV restage). So: weights in LDS, staged once;
// Q-weight area unioned with outstage; 2 barriers; waves_per_eu(4,4).
// Trims this round (instruction-count is the remaining lever — VALU 44%
// + MFMA 10% + DS/trans ~ issue-saturated with no pipe at roofline):
//  (a) native-revolution sin/cos (skips radian range-reduction, ~128
//      ops/lane in the Q phase),
//  (b) softmax without max-subtraction (shift-invariant; logits O(30)
//      max vs exp overflow at 88; saves ~112 ops/lane),
//  (c) DPP 8-lane reduce kept from R7/R8 (correctness proven, replaces
//      ds_swizzle traffic with VALU-fused DPP).
// Spill tripwire: WRITE_SIZE must stay 32768 KB.
__global__ __attribute__((amdgpu_waves_per_eu(4, 4))) __launch_bounds__(256)
void iw_main(const __hip_bfloat16* __restrict__ suppT, const float* __restrict__ flow,
             const float* __restrict__ feat_curr,
             const short8* __restrict__ wg, const float* __restrict__ bias_g,
             const float* __restrict__ q_b, float* __restrict__ out)
{
  // LDS map: [0,16384) K'/V' frags [16][64] short8
  //          [16384,18432) bias as [mat][nt][l15][r] f32 (b128 per lane)
  //          [18432,35072) UNION{ Q frags [16][64] short8 (Q phase only),
  //                               outstage float[64*65] (post-Q) }
  __shared__ __align__(16) char smem[35072];
  short8* lds_kv   = (short8*)smem;
  f32x4*  lds_bias = (f32x4*)(smem + 16384);
  short8* lds_qw   = (short8*)(smem + 18432);
  float*  outstage = (float*)(smem + 18432);

  const int tid = threadIdx.x;
  const int idx = ((blockIdx.x & 7) << 8) | (blockIdx.x >> 3);  // XCD swizzle
  const int b   = idx >> 10;
  const int hw0 = (idx & 1023) << 6;
  const int lane = tid & 63, wv = tid >> 6;
  const int quad = lane >> 4, l15 = lane & 15;
  const int uvl  = l15 & 3;
  const int prow = l15 >> 2;
  const short8* sT = (const short8*)suppT;   // 8 short8 per pixel

  // ---------- stage weights+bias into LDS (all L2-resident, coalesced)
#pragma unroll
  for (int j = 0; j < 4; ++j) {
    lds_qw[j * 256 + tid] = wg[j * 256 + tid];          // Q slots 0..1023
    lds_kv[j * 256 + tid] = wg[1024 + j * 256 + tid];   // K'/V' slots
  }
  {
    float* bl = (float*)lds_bias;
#pragma unroll
    for (int s_ = 0; s_ < 2; ++s_) {
      int s = s_ * 256 + tid;
      int mat = s >> 8, rem = s & 255, r = rem >> 6, c = rem & 63;
      bl[mat * 256 + (c >> 4) * 64 + (c & 15) * 4 + r] = bias_g[s];
    }
  }
  __syncthreads();

  // per-lane inverse dim_t: f = a*16 + quad*4 + jj
  float invd[2][4];
#pragma unroll
  for (int a = 0; a < 2; ++a)
#pragma unroll
    for (int jj = 0; jj < 4; ++jj)
      invd[a][jj] = __expf(-(float)(a * 16 + quad * 4 + jj) * LN1E4_32);

  int iy, ix;              // integer grid base of this lane's Q pixel
  f32x4 qacc[4];

  // ---------- Q phase: A-frag (m = l15 -> pixel), GEMM (K=128), B from LDS
  {
    const int qpix = hw0 + wv * 16 + l15;
    float2 fl = ((const float2*)flow)[b * HWHW + qpix];
    float gy = (float)(qpix >> 8) + fl.y;
    float gx = (float)(qpix & 255) + fl.x;
    float fy = floorf(gy), fx = floorf(gx);
    iy = (int)fy; ix = (int)fx;
    // revolutions: frac/(2+1e-6); trig via v_sin/v_cos (rev in [0,0.5])
    float vy = (gy - fy) * 0.49999975f;
    float vx = (gx - fx) * 0.49999975f;

    short8 qa[4];
#pragma unroll
    for (int ks = 0; ks < 4; ++ks) {
      float val = (ks < 2) ? vy : vx;
#pragma unroll
      for (int jj = 0; jj < 4; ++jj) {
        int c = ks * 16 + quad * 4 + jj;
        float feat = feat_curr[(b * 64 + c) * HWHW + qpix];
        float rev = val * invd[ks & 1][jj];
        qa[ks][jj * 2]     = f2bf(feat + FSIN(rev));
        qa[ks][jj * 2 + 1] = f2bf(feat + FCOS(rev));
      }
    }
#pragma unroll
    for (int nt = 0; nt < 4; ++nt) qacc[nt] = (f32x4){0.f, 0.f, 0.f, 0.f};
#pragma unroll
    for (int ks = 0; ks < 4; ++ks)
#pragma unroll
      for (int nt = 0; nt < 4; ++nt)
        qacc[nt] = __builtin_amdgcn_mfma_f32_16x16x32_bf16(
            qa[ks], lds_qw[(ks * 4 + nt) * 64 + lane], qacc[nt], 0, 0, 0);
  }

  // ---------- gather offsets for all mt, from in-register iy/ix
  int off[4];
#pragma unroll
  for (int m = 0; m < 4; ++m) {
    int p  = m * 4 + prow;
    int yy = min(max(__shfl(iy, p) + (uvl >> 1), 0), 255);
    int xx = min(max(__shfl(ix, p) + (uvl & 1), 0), 255);
    off[m] = (b * HWHW + yy * 256 + xx) * 8;
  }

  // barrier: all waves done reading lds_qw before outstage (same bytes) is
  // written. Drains vmcnt too, so gathers are issued AFTER it.
  __syncthreads();

  // all 8 suppT gathers issued up-front; first consumed after the 64-shfl
  // transpose below + nt=0 weight reads -> deep natural pipeline.
  short8 ka[4][2];
#pragma unroll
  for (int m = 0; m < 4; ++m) {
    ka[m][0] = sT[off[m] + quad];
    ka[m][1] = sT[off[m] + 4 + quad];
  }

  // bias+scale then shuffle-transpose: qT[mt][nt] = q[pixel mt*4+quad][nt*16+l15]
  float qT[4][4];
  {
#pragma unroll
    for (int nt = 0; nt < 4; ++nt) {
      float qb = q_b[nt * 16 + l15];
#pragma unroll
      for (int r = 0; r < 4; ++r)
        qacc[nt][r] = (qacc[nt][r] + qb) * 0.35355339059327373f;
    }
#pragma unroll
    for (int mt = 0; mt < 4; ++mt)
#pragma unroll
      for (int nt = 0; nt < 4; ++nt) {
        int src = mt * 16 + l15;
        float v0 = __shfl(qacc[nt][0], src);
        float v1 = __shfl(qacc[nt][1], src);
        float v2 = __shfl(qacc[nt][2], src);
        float v3 = __shfl(qacc[nt][3], src);
        float t0 = (quad & 2) ? v2 : v0;
        float t1 = (quad & 2) ? v3 : v1;
        qT[mt][nt] = (quad & 1) ? t1 : t0;
      }
  }

  // ---------- K/V + attention. nt outer: weights+bias read once per nt
  // from LDS (16 regs); mt inner consumes the prefetched ka[mt].
#pragma unroll
  for (int nt = 0; nt < 4; ++nt) {
    short8 kf0 = lds_kv[nt * 64 + lane];
    short8 kf1 = lds_kv[(4 + nt) * 64 + lane];
    short8 vf0 = lds_kv[(8 + nt) * 64 + lane];
    short8 vf1 = lds_kv[(12 + nt) * 64 + lane];
    f32x4 kb4 = lds_bias[nt * 16 + l15];        // [0][nt][l15][r]
    f32x4 vb4 = lds_bias[64 + nt * 16 + l15];   // [1][nt][l15][r]

#pragma unroll
    for (int mt = 0; mt < 4; ++mt) {
      f32x4 kacc = kb4;   // bias rides in the MFMA C-operand (reg r == uv r)
      f32x4 vacc = vb4;
      kacc = __builtin_amdgcn_mfma_f32_16x16x32_bf16(ka[mt][0], kf0, kacc, 0, 0, 0);
      kacc = __builtin_amdgcn_mfma_f32_16x16x32_bf16(ka[mt][1], kf1, kacc, 0, 0, 0);
      vacc = __builtin_amdgcn_mfma_f32_16x16x32_bf16(ka[mt][0], vf0, vacc, 0, 0, 0);
      vacc = __builtin_amdgcn_mfma_f32_16x16x32_bf16(ka[mt][1], vf1, vacc, 0, 0, 0);

      // D rows: pixel = mt*4+quad, uv = reg r. Head channels span 8 lanes.
      // 8-lane sum via DPP: xor1 (0xB1), xor2 (0x4E), row_half_mirror
      // (0x141) — valid: quad sums are uniform per quad at the last step.
      float lg[4];
#pragma unroll
      for (int r = 0; r < 4; ++r) {
        float p = qT[mt][nt] * kacc[r];
        p += __int_as_float(__builtin_amdgcn_update_dpp(
                 0, __float_as_int(p), 0xB1, 0xf, 0xf, true));
        p += __int_as_float(__builtin_amdgcn_update_dpp(
                 0, __float_as_int(p), 0x4E, 0xf, 0xf, true));
        p += __int_as_float(__builtin_amdgcn_update_dpp(
                 0, __float_as_int(p), 0x141, 0xf, 0xf, true));
        lg[r] = p;
      }
      // softmax without max-subtraction: logits bounded (|lg| << 88)
      float e0 = __expf(lg[0]), e1 = __expf(lg[1]);
      float e2 = __expf(lg[2]), e3 = __expf(lg[3]);
      float inv = 1.0f / (e0 + e1 + e2 + e3);
      float o = (e0 * vacc[0] + e1 * vacc[1] + e2 * vacc[2] + e3 * vacc[3]) * inv;
      outstage[(nt * 16 + l15) * 65 + wv * 16 + mt * 4 + quad] = o;
    }
  }

  // ---------- coalesced full-line write-out
  __syncthreads();
#pragma unroll
  for (int i = 0; i < 16; ++i) {
    int j = i * 256 + tid;
    int c = j >> 6, p = j & 63;
    out[(b * 64 + c) * HWHW + hw0 + p] = outstage[c * 65 + p];
  }
}

extern "C" void kernel_launch(void* const* d_in, const int* in_sizes, int n_in,
                              void* d_out, int out_size, void* d_ws, size_t ws_size,
                              hipStream_t stream) {
  const float* feat_supp = (const float*)d_in[0];
  const float* flow      = (const float*)d_in[1];
  const float* feat_curr = (const float*)d_in[2];
  const float* q_w = (const float*)d_in[3];
  const float* q_b = (const float*)d_in[4];
  const float* k_w = (const float*)d_in[5];
  const float* k_b = (const float*)d_in[6];
  const float* v_w = (const float*)d_in[7];
  const float* v_b = (const float*)d_in[8];
  float* out = (float*)d_out;
  (void)in_sizes; (void)n_in; (void)out_size; (void)ws_size;

  __hip_bfloat16* wfrag = (__hip_bfloat16*)d_ws;
  float* bias           = (float*)((char*)d_ws + 32768);
  __hip_bfloat16* suppT = (__hip_bfloat16*)((char*)d_ws + 65536);

  hipLaunchKernelGGL(pre_pass, dim3(2057), dim3(256), 0, stream,
                     feat_supp, q_w, k_w, v_w, k_b, v_b, suppT, wfrag, bias);
  hipLaunchKernelGGL(iw_main, dim3(2048), dim3(256), 0, stream,
                     suppT, flow, feat_curr, (const short8*)d_ws, bias, q_b, out);
}

// Round 10
// 145.414 us; speedup vs baseline: 1.1273x; 1.0063x over previous
//
#include <hip/hip_runtime.h>
#include <hip/hip_bf16.h>

#define HWHW 65536   // 256*256
#define LN1E4_32 0.28782313662425572f   // ln(10000)/32
#define TWO_PI_N 6.2831847f              // 2*pi / 1.000001

typedef __attribute__((ext_vector_type(8))) short short8;
typedef __attribute__((ext_vector_type(4))) short s16x4;   // 'short4' taken by HIP
typedef __attribute__((ext_vector_type(4))) float f32x4;

// native-revolution trig: v_sin_f32/v_cos_f32 take REVOLUTIONS (ISA).
// rev inputs here are in [0, 0.5] so no range reduction is needed.
#if __has_builtin(__builtin_amdgcn_sinf) && __has_builtin(__builtin_amdgcn_cosf)
#define FSIN(x) __builtin_amdgcn_sinf(x)
#define FCOS(x) __builtin_amdgcn_cosf(x)
#else
#define FSIN(x) __sinf((x) * 6.2831853071795864f)
#define FCOS(x) __cosf((x) * 6.2831853071795864f)
#endif

// d_ws layout:
//   [0, 32768)        : wfrag bf16 — Q slots 0..1023 (K=128, PRE-SCALED by
//                       1/sqrt(8)), K' 1024..1535, V' 1536..2047 (K=64,
//                       pair-summed weights)
//   [32768, 34816)    : bias tables fp32 — peK·Wk+k_b [4][64], then peV·Wv+v_b
//   [65536, 16842752) : feat_supp transposed (B,HW,C) bf16
// REQUIRES ws_size >= 16842752.

__device__ __forceinline__ short f2bf(float f) {
  union { __hip_bfloat16 h; short s; } u;
  u.h = __float2bfloat16(f);
  return u.s;
}

// ---------------- merged pre-pass (R1 version — measured ~BW-floor, keep):
//   blocks 0..2047    : feat_supp (B,C,HW) f32 -> (B,HW,C) bf16 transpose
//   blocks 2048..2055 : weight fragment packing
//   block  2056       : PE-folded bias tables
__global__ __launch_bounds__(256)
void pre_pass(const float* __restrict__ supp,
              const float* __restrict__ qw, const float* __restrict__ kw,
              const float* __restrict__ vw,
              const float* __restrict__ kb, const float* __restrict__ vb,
              __hip_bfloat16* __restrict__ suppT,
              __hip_bfloat16* __restrict__ wfrag, float* __restrict__ bias) {
  const int t = threadIdx.x;
  if (blockIdx.x < 2048) {
    __shared__ short tile[64 * 68];     // 8.7 KB
    const int b   = blockIdx.x >> 10;
    const int p0  = (blockIdx.x & 1023) << 6;
    const int px4 = (t & 15) << 2;      // pixel group 0,4,..,60
    const int g   = t >> 4;             // channel quad 0..15

    const float* src = supp + ((size_t)b * 64 + g * 4) * HWHW + p0 + px4;
    f32x4 v[4];
#pragma unroll
    for (int c = 0; c < 4; ++c)
      v[c] = *(const f32x4*)(src + (size_t)c * HWHW);
#pragma unroll
    for (int j = 0; j < 4; ++j) {
      s16x4 pk;
#pragma unroll
      for (int c = 0; c < 4; ++c) pk[c] = f2bf(v[c][j]);
      *(s16x4*)&tile[(px4 + j) * 68 + g * 4] = pk;
    }
    __syncthreads();
    const int px = t >> 2, ch0 = (t & 3) << 4;
    s16x4 r0 = *(s16x4*)&tile[px * 68 + ch0];
    s16x4 r1 = *(s16x4*)&tile[px * 68 + ch0 + 4];
    s16x4 r2 = *(s16x4*)&tile[px * 68 + ch0 + 8];
    s16x4 r3 = *(s16x4*)&tile[px * 68 + ch0 + 12];
    short8 o0, o1;
#pragma unroll
    for (int j = 0; j < 4; ++j) {
      o0[j] = r0[j]; o0[j + 4] = r1[j];
      o1[j] = r2[j]; o1[j + 4] = r3[j];
    }
    short8* dst = (short8*)(suppT + ((size_t)(b * HWHW + p0 + px)) * 64 + ch0);
    dst[0] = o0;
    dst[1] = o1;
  } else if (blockIdx.x < 2056) {
    // ---- weight fragments. B layout: n=nt*16+(lane&15), k=ks*32+(lane>>4)*8+j
    int slot = (blockIdx.x - 2048) * 256 + t;     // 0..2047
    __hip_bfloat16* dst = wfrag + slot * 8;
    if (slot < 1024) {               // Q (K=128), pre-scaled by 1/sqrt(hd)
      int ksnt = slot >> 6, lane = slot & 63;
      int ks = ksnt >> 2, nt = ksnt & 3;
      const float* w = qw + (nt * 16 + (lane & 15)) * 128 + ks * 32 + (lane >> 4) * 8;
#pragma unroll
      for (int j = 0; j < 8; ++j)
        dst[j] = __float2bfloat16(w[j] * 0.35355339059327373f);
    } else {                         // K'/V': K=64, W'[n][c] = W[n][2c]+W[n][2c+1]
      int mat = (slot >= 1536);
      int rem = slot & 511;
      int ksnt = rem >> 6, lane = rem & 63;
      int ks = ksnt >> 2, nt = ksnt & 3;          // ks 0..1
      int c0 = ks * 32 + (lane >> 4) * 8;
      const float* w = (mat ? vw : kw) + (nt * 16 + (lane & 15)) * 128;
#pragma unroll
      for (int j = 0; j < 8; ++j)
        dst[j] = __float2bfloat16(w[2 * (c0 + j)] + w[2 * (c0 + j) + 1]);
    }
  } else {
    // ---- bias[mat*256 + uv*64 + c] = b[c] + sum_kk pe[uv][kk] * W[c][kk]
    for (int s = t; s < 512; s += 256) {
      int mat = s >> 8, uv = (s >> 6) & 3, c = s & 63;
      const float* w = (mat ? vw : kw) + c * 128;
      float acc = (mat ? vb : kb)[c];
      for (int kk = 0; kk < 128; ++kk) {
        float val = (kk < 64 ? (float)(uv >> 1) : (float)(uv & 1)) * TWO_PI_N;
        int i = kk & 63, f = i >> 1;
        float arg = val * __expf(-(float)f * LN1E4_32);
        float pe = (i & 1) ? __cosf(arg) : __sinf(arg);
        acc += pe * w[kk];
      }
      bias[s] = acc;
    }
  }
}

// ---------------- main: 64 px/block, 4 waves.
// R10 = R9 (R5 structure + VALU trims, total 146.3, iw_main ~35) MINUS the
// 64-shfl Q transpose. Key identity: the Q MFMA's D-layout is
// D[m=quad*4+reg][n=nt*16+l15]; the KV loop wants q[pixel=mt*4+quad].
// Choosing the A-frag pixel mapping m -> sigma(m) (sigma swaps the two
// 2-bit fields, an involution) makes qacc[nt][mt] == qT[mt][nt] DIRECTLY:
// pixel(sigma(quad*4+mt)) = mt*4+quad. Coalescing unchanged (same pixel
// set per 16-lane group). Epilogue fully deleted: 1/sqrt(8) pre-folded
// into the Q weights (pre_pass), q_b*scale rides the MFMA C-operand.
// Gather-offset shuffles permute the src lane (src = prow*4+m). Gathers
// now issue BEFORE the Q MFMAs (16 MFMA + ds_read cover; drained at B2).
// ~130 VALU/DS ops removed per lane; one serialization point removed.
// Spill tripwire: WRITE_SIZE must stay 32768 KB.
__global__ __attribute__((amdgpu_waves_per_eu(4, 4))) __launch_bounds__(256)
void iw_main(const __hip_bfloat16* __restrict__ suppT, const float* __restrict__ flow,
             const float* __restrict__ feat_curr,
             const short8* __restrict__ wg, const float* __restrict__ bias_g,
             const float* __restrict__ q_b, float* __restrict__ out)
{
  // LDS map: [0,16384) K'/V' frags [16][64] short8
  //          [16384,18432) bias as [mat][nt][l15][r] f32 (b128 per lane)
  //          [18432,35072) UNION{ Q frags [16][64] short8 (Q phase only),
  //                               outstage float[64*65] (post-Q) }
  __shared__ __align__(16) char smem[35072];
  short8* lds_kv   = (short8*)smem;
  f32x4*  lds_bias = (f32x4*)(smem + 16384);
  short8* lds_qw   = (short8*)(smem + 18432);
  float*  outstage = (float*)(smem + 18432);

  const int tid = threadIdx.x;
  const int idx = ((blockIdx.x & 7) << 8) | (blockIdx.x >> 3);  // XCD swizzle
  const int b   = idx >> 10;
  const int hw0 = (idx & 1023) << 6;
  const int lane = tid & 63, wv = tid >> 6;
  const int quad = lane >> 4, l15 = lane & 15;
  const int uvl  = l15 & 3;
  const int prow = l15 >> 2;
  const int qsel = ((l15 & 3) << 2) | (l15 >> 2);   // sigma: 2-bit-field swap
  const short8* sT = (const short8*)suppT;   // 8 short8 per pixel

  // ---------- stage weights+bias into LDS (all L2-resident, coalesced)
#pragma unroll
  for (int j = 0; j < 4; ++j) {
    lds_qw[j * 256 + tid] = wg[j * 256 + tid];          // Q slots 0..1023
    lds_kv[j * 256 + tid] = wg[1024 + j * 256 + tid];   // K'/V' slots
  }
  {
    float* bl = (float*)lds_bias;
#pragma unroll
    for (int s_ = 0; s_ < 2; ++s_) {
      int s = s_ * 256 + tid;
      int mat = s >> 8, rem = s & 255, r = rem >> 6, c = rem & 63;
      bl[mat * 256 + (c >> 4) * 64 + (c & 15) * 4 + r] = bias_g[s];
    }
  }
  __syncthreads();                                   // B1: staged

  // per-lane inverse dim_t: f = a*16 + quad*4 + jj
  float invd[2][4];
#pragma unroll
  for (int a = 0; a < 2; ++a)
#pragma unroll
    for (int jj = 0; jj < 4; ++jj)
      invd[a][jj] = __expf(-(float)(a * 16 + quad * 4 + jj) * LN1E4_32);

  f32x4 qacc[4];
  short8 ka[4][2];

  // ---------- Q phase: A-frag row m -> pixel sigma(m); GEMM (K=128), B from LDS
  {
    const int qpix = hw0 + wv * 16 + qsel;
    float2 fl = ((const float2*)flow)[b * HWHW + qpix];
    float gy = (float)(qpix >> 8) + fl.y;
    float gx = (float)(qpix & 255) + fl.x;
    float fy = floorf(gy), fx = floorf(gx);
    int iy = (int)fy, ix = (int)fx;
    // revolutions: frac/(2+1e-6); trig via v_sin/v_cos (rev in [0,0.5])
    float vy = (gy - fy) * 0.49999975f;
    float vx = (gx - fx) * 0.49999975f;

    short8 qa[4];
#pragma unroll
    for (int ks = 0; ks < 4; ++ks) {
      float val = (ks < 2) ? vy : vx;
#pragma unroll
      for (int jj = 0; jj < 4; ++jj) {
        int c = ks * 16 + quad * 4 + jj;
        float feat = feat_curr[(b * 64 + c) * HWHW + qpix];
        float rev = val * invd[ks & 1][jj];
        qa[ks][jj * 2]     = f2bf(feat + FSIN(rev));
        qa[ks][jj * 2 + 1] = f2bf(feat + FCOS(rev));
      }
    }

    // gather offsets: pixel p=m*4+prow lives at lane sigma(p)=prow*4+m
#pragma unroll
    for (int m = 0; m < 4; ++m) {
      int src = prow * 4 + m;
      int yy = min(max(__shfl(iy, src) + (uvl >> 1), 0), 255);
      int xx = min(max(__shfl(ix, src) + (uvl & 1), 0), 255);
      int off = (b * HWHW + yy * 256 + xx) * 8;
      ka[m][0] = sT[off + quad];              // issued pre-MFMA: 16 MFMAs
      ka[m][1] = sT[off + 4 + quad];          // + ds_reads of cover
    }

    // q_b*scale rides the C-operand (bias per output col n, all rows m)
#pragma unroll
    for (int nt = 0; nt < 4; ++nt) {
      float qb = q_b[nt * 16 + l15] * 0.35355339059327373f;
      qacc[nt] = (f32x4){qb, qb, qb, qb};
    }
#pragma unroll
    for (int ks = 0; ks < 4; ++ks)
#pragma unroll
      for (int nt = 0; nt < 4; ++nt)
        qacc[nt] = __builtin_amdgcn_mfma_f32_16x16x32_bf16(
            qa[ks], lds_qw[(ks * 4 + nt) * 64 + lane], qacc[nt], 0, 0, 0);
  }
  // qacc[nt][mt] == q[pixel hw0+wv*16+mt*4+quad][n=nt*16+l15] * s + qb*s
  // — no transpose, no epilogue.

  // barrier: lds_qw reads done before outstage (same bytes) is written;
  // also drains the 8 gathers (vmcnt(0) at barrier).
  __syncthreads();                                   // B2

  // ---------- K/V + attention. nt outer: weights+bias read once per nt
  // from LDS (16 regs); mt inner consumes the prefetched ka[mt].
#pragma unroll
  for (int nt = 0; nt < 4; ++nt) {
    short8 kf0 = lds_kv[nt * 64 + lane];
    short8 kf1 = lds_kv[(4 + nt) * 64 + lane];
    short8 vf0 = lds_kv[(8 + nt) * 64 + lane];
    short8 vf1 = lds_kv[(12 + nt) * 64 + lane];
    f32x4 kb4 = lds_bias[nt * 16 + l15];        // [0][nt][l15][r]
    f32x4 vb4 = lds_bias[64 + nt * 16 + l15];   // [1][nt][l15][r]

#pragma unroll
    for (int mt = 0; mt < 4; ++mt) {
      f32x4 kacc = kb4;   // bias rides in the MFMA C-operand (reg r == uv r)
      f32x4 vacc = vb4;
      kacc = __builtin_amdgcn_mfma_f32_16x16x32_bf16(ka[mt][0], kf0, kacc, 0, 0, 0);
      kacc = __builtin_amdgcn_mfma_f32_16x16x32_bf16(ka[mt][1], kf1, kacc, 0, 0, 0);
      vacc = __builtin_amdgcn_mfma_f32_16x16x32_bf16(ka[mt][0], vf0, vacc, 0, 0, 0);
      vacc = __builtin_amdgcn_mfma_f32_16x16x32_bf16(ka[mt][1], vf1, vacc, 0, 0, 0);

      // D rows: pixel = mt*4+quad, uv = reg r. Head channels span 8 lanes.
      // 8-lane sum via DPP: xor1 (0xB1), xor2 (0x4E), row_half_mirror
      // (0x141) — valid: quad sums are uniform per quad at the last step.
      float lg[4];
#pragma unroll
      for (int r = 0; r < 4; ++r) {
        float p = qacc[nt][mt] * kacc[r];
        p += __int_as_float(__builtin_amdgcn_update_dpp(
                 0, __float_as_int(p), 0xB1, 0xf, 0xf, true));
        p += __int_as_float(__builtin_amdgcn_update_dpp(
                 0, __float_as_int(p), 0x4E, 0xf, 0xf, true));
        p += __int_as_float(__builtin_amdgcn_update_dpp(
                 0, __float_as_int(p), 0x141, 0xf, 0xf, true));
        lg[r] = p;
      }
      // softmax without max-subtraction: logits bounded (|lg| << 88)
      float e0 = __expf(lg[0]), e1 = __expf(lg[1]);
      float e2 = __expf(lg[2]), e3 = __expf(lg[3]);
      float inv = 1.0f / (e0 + e1 + e2 + e3);
      float o = (e0 * vacc[0] + e1 * vacc[1] + e2 * vacc[2] + e3 * vacc[3]) * inv;
      outstage[(nt * 16 + l15) * 65 + wv * 16 + mt * 4 + quad] = o;
    }
  }

  // ---------- coalesced full-line write-out
  __syncthreads();
#pragma unroll
  for (int i = 0; i < 16; ++i) {
    int j = i * 256 + tid;
    int c = j >> 6, p = j & 63;
    out[(b * 64 + c) * HWHW + hw0 + p] = outstage[c * 65 + p];
  }
}

extern "C" void kernel_launch(void* const* d_in, const int* in_sizes, int n_in,
                              void* d_out, int out_size, void* d_ws, size_t ws_size,
                              hipStream_t stream) {
  const float* feat_supp = (const float*)d_in[0];
  const float* flow      = (const float*)d_in[1];
  const float* feat_curr = (const float*)d_in[2];
  const float* q_w = (const float*)d_in[3];
  const float* q_b = (const float*)d_in[4];
  const float* k_w = (const float*)d_in[5];
  const float* k_b = (const float*)d_in[6];
  const float* v_w = (const float*)d_in[7];
  const float* v_b = (const float*)d_in[8];
  float* out = (float*)d_out;
  (void)in_sizes; (void)n_in; (void)out_size; (void)ws_size;

  __hip_bfloat16* wfrag = (__hip_bfloat16*)d_ws;
  float* bias           = (float*)((char*)d_ws + 32768);
  __hip_bfloat16* suppT = (__hip_bfloat16*)((char*)d_ws + 65536);

  hipLaunchKernelGGL(pre_pass, dim3(2057), dim3(256), 0, stream,
                     feat_supp, q_w, k_w, v_w, k_b, v_b, suppT, wfrag, bias);
  hipLaunchKernelGGL(iw_main, dim3(2048), dim3(256), 0, stream,
                     suppT, flow, feat_curr, (const short8*)d_ws, bias, q_b, out);
}